// Round 6
// baseline (124.503 us; speedup 1.0000x reference)
//
#include <hip/hip_runtime.h>
#include <math.h>

// ---------------- problem constants ----------------
#define NBLOCKS 2048
#define THREADS 512               // 8 waves/block (R5: halve per-wave state, double TLP)
#define TILE 64
#define POS_PER_BLOCK 512         // one j-row per block: i, b constant
#define ITERS 8
#define CH 512                    // ushorts per k'-chunk: 64 pos * 8

typedef __attribute__((ext_vector_type(8)))  short  short8;   // MFMA A/B frag
typedef __attribute__((ext_vector_type(4)))  float  float4v;
typedef __attribute__((ext_vector_type(4)))  unsigned uint4v;
typedef __attribute__((ext_vector_type(16))) float  float16;  // 32x32 C/D frag

// gfx950 packed f32x2 -> bf16x2 (RNE), single VALU instruction
__device__ __forceinline__ unsigned cvt_pk(float lo, float hi) {
    unsigned r;
    asm("v_cvt_pk_bf16_f32 %0, %1, %2" : "=v"(r) : "v"(lo), "v"(hi));
    return r;
}

// NOTE (R1/R2 session evidence): replacing the fmaxf-pair relu with
// v_pk_max_i16-on-packed-bf16 produced NaN output in two independent runs.
// Do NOT reintroduce it.

// k'-chunk map: chunk c (0..15), elem jj (0..7) -> channel.
// chunk c = 4*tile + 2*m + lh holds ch_local = (jj&3) + 8*(jj>>2) + 4lh + 16m,
// which is exactly the 32x32 MFMA C-reg octet m of a lane -> b128 everywhere.
__device__ __forceinline__ int kmap(int c, int jj) {
    return 32 * (c >> 2) + 16 * ((c >> 1) & 1) + 4 * (c & 1) + ((jj >> 2) << 3) + (jj & 3);
}

// R5 geometry: 8 waves, wave = (ct 0..3, ph 0..1); 2 blocks/CU = 16 waves/CU.
// R6: kernel is critical-path-bound (R4: deleting VALU didn't help; R5:
// doubling occupancy barely helped -> correlated barrier stalls). This round
// shortens the per-iter dependency path: bias hoisted to regs (kills LDS
// latency at phase-B head), 8-dep MFMA chain split 2x4, layer-3 de-serialized.
__global__ __launch_bounds__(512, 4)
void crpb_mfma8(const float* __restrict__ gq,   // (512,3)
                const float* __restrict__ gkv,  // (4,512,3)
                const float* __restrict__ W1,   // (3,128)
                const float* __restrict__ b1,   // (128,)
                const float* __restrict__ W2,   // (128,128)
                const float* __restrict__ b2,   // (128,)
                const float* __restrict__ W3,   // (128,4)
                const float* __restrict__ b3,   // (4,)
                float* __restrict__ out)        // (16,512,512)
{
    __shared__ __align__(16) unsigned short ash[2][16 * CH];   // 2 x 16 KB h1 tile
    __shared__ __align__(16) float red[2][4 * 4 * 64];         // 2 x 4 KB partials [ct][o][pos]
    // per-block feature table (one j-row), B-frag word layout (R4).
    __shared__ __align__(16) unsigned fA[512][4];              // 8 KB
    __shared__ __align__(16) unsigned fB[512];                 // 2 KB

    const int tid  = threadIdx.x;
    const int lane = tid & 63;
    const int w    = __builtin_amdgcn_readfirstlane(tid >> 6);  // 0..7
    const int l31  = lane & 31;
    const int lh   = lane >> 5;

    // wave role: ch-tile ct (32 chs), pos-half ph
    const int ct = w & 3;
    const int ph = w >> 2;
    const int pofs = ph * 32 + l31;     // this lane's position within tile

    // persistent zero C-operand (shared by layer-1 and layer-3 MFMAs)
    float16 z16;
    #pragma unroll
    for (int r = 0; r < 16; ++r) z16[r] = 0.0f;

    // ---- b2 bias hoisted to registers (R6): C-layout row = (t)+8*qr+4*lh ----
    float binit[16];
    #pragma unroll
    for (int qr = 0; qr < 4; ++qr) {
        const float4v bv = *(const float4v*)&b2[ct * 32 + 8 * qr + 4 * lh];
        #pragma unroll
        for (int t = 0; t < 4; ++t) binit[4 * qr + t] = bv[t];
    }

    // ---- layer-1 A-frag for this wave's ch tile (W1 hi/lo + b1 folded) ----
    // lh0 slots: (w0h,w0l),(w0h,w1h),(w1l,w1h),(w2h,w2l)  <-> B: (f0h,f0h),(f0l,f1h),(f1h,f1l),(f2h,f2h)
    // lh1 slots: (w2h,b1h),(b1l,0),0,0                    <-> B: (f2l,1.0),(1.0,0),0,0
    short8 w1f;
    {
        const int ch = ct * 32 + l31;
        const float w0 = W1[ch], w1v = W1[128 + ch], w2v = W1[256 + ch], b1v = b1[ch];
        const float w0h = __uint_as_float(cvt_pk(w0, w0) << 16);
        const float w1h = __uint_as_float(cvt_pk(w1v, w1v) << 16);
        const float w2h = __uint_as_float(cvt_pk(w2v, w2v) << 16);
        const float b1h = __uint_as_float(cvt_pk(b1v, b1v) << 16);
        const float w0l = w0 - w0h, w1l = w1v - w1h, w2l = w2v - w2h, b1l = b1v - b1h;
        unsigned d[4];
        if (lh == 0) {
            d[0] = cvt_pk(w0h, w0l);
            d[1] = cvt_pk(w0h, w1h);
            d[2] = cvt_pk(w1l, w1h);
            d[3] = cvt_pk(w2h, w2l);
        } else {
            d[0] = cvt_pk(w2h, b1h);
            d[1] = cvt_pk(b1l, 0.0f);
            d[2] = 0; d[3] = 0;
        }
        __builtin_memcpy(&w1f, d, 16);
    }

    // ---- W2^T A-frags for this wave's 32 out-chs (32 VGPRs) ----
    short8 a2f[8];
    {
        const int e = ct * 32 + l31;
        #pragma unroll
        for (int ks = 0; ks < 8; ++ks) {
            const int c = 2 * ks + lh;
            unsigned t0[4];
            #pragma unroll
            for (int t = 0; t < 4; ++t) {
                const int d0 = kmap(c, 2 * t), d1 = d0 + 1;
                t0[t] = cvt_pk(W2[d0 * 128 + e], W2[d1 * 128 + e]);
            }
            __builtin_memcpy(&a2f[ks], t0, 16);
        }
    }

    // ---- W3 A-frags: 2 frags cover this wave's 32 chs (8 VGPRs) ----
    short8 w3a[2];
    #pragma unroll
    for (int m2 = 0; m2 < 2; ++m2) {
        unsigned tt[4];
        #pragma unroll
        for (int t = 0; t < 4; ++t) {
            const int chl = ((2 * t) & 3) + 8 * ((2 * t) >> 2) + 4 * lh + 16 * m2;
            const int ch0 = ct * 32 + chl, ch1 = ch0 + 1;
            const float lo = (l31 < 4) ? W3[ch0 * 4 + l31] : 0.0f;
            const float hi = (l31 < 4) ? W3[ch1 * 4 + l31] : 0.0f;
            tt[t] = cvt_pk(lo, hi);
        }
        __builtin_memcpy(&w3a[m2], tt, 16);
    }
    const float b3r = b3[w & 3];   // phase R: waves 0..3, o = w

    // block-constant: one j-row (b, i fixed)
    const int posblock = blockIdx.x * POS_PER_BLOCK;
    const int bb = posblock >> 18;
    const int i  = (posblock >> 9) & 511;
    const float q0 = gq[i * 3 + 0], q1 = gq[i * 3 + 1], q2 = gq[i * 3 + 2];
    const float* kvrow = gkv + (size_t)(bb << 9) * 3;

    // ---- feature precompute: whole j-row, once per block (1 pos/thread) ----
    for (int jj = tid; jj < 512; jj += THREADS) {
        const float k0 = kvrow[jj * 3 + 0], k1 = kvrow[jj * 3 + 1], k2 = kvrow[jj * 3 + 2];
        const float c0 = q0 - k0, c1 = q1 - k1, c2 = q2 - k2;
        const float f0 = copysignf(__logf(1.0f + fabsf(c0)), c0);
        const float f1 = copysignf(__logf(1.0f + fabsf(c1)), c1);
        const float f2 = copysignf(__logf(1.0f + fabsf(c2)), c2);
        const unsigned u0 = cvt_pk(f0, f0), u2 = cvt_pk(f2, f2);
        const float f0h = __uint_as_float(u0 << 16);
        const float f1h = __uint_as_float(cvt_pk(f1, f1) << 16);
        const float f2h = __uint_as_float(u2 << 16);
        const float f0l = f0 - f0h, f1l = f1 - f1h, f2l = f2 - f2h;
        fA[jj][0] = u0;                    // (f0h, f0h)
        fA[jj][1] = cvt_pk(f0l, f1);       // (f0l, f1h)
        fA[jj][2] = cvt_pk(f1, f1l);       // (f1h, f1l)
        fA[jj][3] = u2;                    // (f2h, f2h)
        fB[jj]    = cvt_pk(f2l, 1.0f);     // (f2l, 1.0) ; word1 is const
    }
    __syncthreads();   // features visible to all waves

    // ======== phase A: B-frag from LDS -> layer-1 MFMA -> ash[buf] ========
    auto phaseA = [&](int x, int buf) {
        const int jpos = x * TILE + pofs;
        unsigned d[4];
        if (lh == 0) {
            const uint4v t = *(const uint4v*)&fA[jpos][0];
            d[0] = t[0]; d[1] = t[1]; d[2] = t[2]; d[3] = t[3];
        } else {
            d[0] = fB[jpos];
            d[1] = 0x00003F80u;            // (bf16 1.0, 0) <- picks up b1
            d[2] = 0; d[3] = 0;
        }
        short8 bf; __builtin_memcpy(&bf, d, 16);

        float16 c1r = __builtin_amdgcn_mfma_f32_32x32x16_bf16(w1f, bf, z16, 0, 0, 0);
        unsigned pk0[4], pk1[4];
        #pragma unroll
        for (int t = 0; t < 4; ++t) {
            pk0[t] = cvt_pk(fmaxf(c1r[2 * t], 0.f),     fmaxf(c1r[2 * t + 1], 0.f));
            pk1[t] = cvt_pk(fmaxf(c1r[8 + 2 * t], 0.f), fmaxf(c1r[8 + 2 * t + 1], 0.f));
        }
        short8 v0, v1;
        __builtin_memcpy(&v0, pk0, 16);
        __builtin_memcpy(&v1, pk1, 16);
        *(short8*)&ash[buf][(4 * ct + lh) * CH + pofs * 8]     = v0;   // m=0 octet
        *(short8*)&ash[buf][(4 * ct + 2 + lh) * CH + pofs * 8] = v1;   // m=1 octet
    };

    phaseA(0, 0);
    __syncthreads();   // fences ash[0]

    for (int it = 0; it < ITERS; ++it) {
        const int buf = it & 1;
        const int jb = it * TILE;

        // ======== phase B: layer-2; 8 B-reads feed 8 MFMAs as 2x4 chains ========
        float16 acc_a, acc_b;
        #pragma unroll
        for (int r = 0; r < 16; ++r) acc_a[r] = binit[r];
        const unsigned short* br = &ash[buf][lh * CH + pofs * 8];

        // T5: boost issue priority through the dense MFMA region (R3: -2.7%).
        __builtin_amdgcn_s_setprio(1);
        {
            // chain A: ks 0..3 (bias-seeded); chain B: ks 4..7 (zero-seeded);
            // independent -> dep-latency exposure halves; merge folds into relu.
            short8 bf0 = *(const short8*)(br + 0 * 2 * CH);
            short8 bf4 = *(const short8*)(br + 4 * 2 * CH);
            acc_a = __builtin_amdgcn_mfma_f32_32x32x16_bf16(a2f[0], bf0, acc_a, 0, 0, 0);
            acc_b = __builtin_amdgcn_mfma_f32_32x32x16_bf16(a2f[4], bf4, z16, 0, 0, 0);
            #pragma unroll
            for (int ks = 1; ks < 4; ++ks) {
                short8 bfa = *(const short8*)(br + ks * 2 * CH);
                short8 bfb = *(const short8*)(br + (ks + 4) * 2 * CH);
                acc_a = __builtin_amdgcn_mfma_f32_32x32x16_bf16(a2f[ks],     bfa, acc_a, 0, 0, 0);
                acc_b = __builtin_amdgcn_mfma_f32_32x32x16_bf16(a2f[ks + 4], bfb, acc_b, 0, 0, 0);
            }
        }

        // ======== phase C': relu(acc_a+acc_b) + layer-3 (2 independent MFMAs) ========
        {
            unsigned pa0[4], pa1[4];
            #pragma unroll
            for (int t = 0; t < 4; ++t) {
                pa0[t] = cvt_pk(fmaxf(acc_a[2 * t]     + acc_b[2 * t], 0.f),
                                fmaxf(acc_a[2 * t + 1] + acc_b[2 * t + 1], 0.f));
                pa1[t] = cvt_pk(fmaxf(acc_a[8 + 2 * t]     + acc_b[8 + 2 * t], 0.f),
                                fmaxf(acc_a[8 + 2 * t + 1] + acc_b[8 + 2 * t + 1], 0.f));
            }
            short8 fa0, fa1;
            __builtin_memcpy(&fa0, pa0, 16); __builtin_memcpy(&fa1, pa1, 16);
            float16 p0 = __builtin_amdgcn_mfma_f32_32x32x16_bf16(w3a[0], fa0, z16, 0, 0, 0);
            float16 p1 = __builtin_amdgcn_mfma_f32_32x32x16_bf16(w3a[1], fa1, z16, 0, 0, 0);
            __builtin_amdgcn_s_setprio(0);
            if (lh == 0) {
                #pragma unroll
                for (int o = 0; o < 4; ++o)
                    red[buf][ct * 256 + o * 64 + pofs] = p0[o] + p1[o];
            }
        }

        // ======== phase A for next tile (other ash buffer) ========
        if (it != ITERS - 1) phaseA(it + 1, 1 - buf);

        __syncthreads();   // single barrier/tile: fences ash[1-buf] and red[buf]

        // ======== phase R: sum 4 ct-partials + b3, coalesced store (waves 0..3) ========
        if (w < 4) {
            const int o = w, pos = lane;
            const float v = b3r
                          + red[buf][0 * 256 + o * 64 + pos]
                          + red[buf][1 * 256 + o * 64 + pos]
                          + red[buf][2 * 256 + o * 64 + pos]
                          + red[buf][3 * 256 + o * 64 + pos];
            out[((size_t)((bb << 2) + o) << 18) + ((size_t)i << 9) + jb + pos] = v;
        }
    }
}

extern "C" void kernel_launch(void* const* d_in, const int* in_sizes, int n_in,
                              void* d_out, int out_size, void* d_ws, size_t ws_size,
                              hipStream_t stream) {
    const float* gq  = (const float*)d_in[0];
    const float* gkv = (const float*)d_in[1];
    const float* W1  = (const float*)d_in[2];
    const float* b1  = (const float*)d_in[3];
    const float* W2  = (const float*)d_in[4];
    const float* b2  = (const float*)d_in[5];
    const float* W3  = (const float*)d_in[6];
    const float* b3  = (const float*)d_in[7];
    float* out = (float*)d_out;

    crpb_mfma8<<<NBLOCKS, THREADS, 0, stream>>>(gq, gkv, W1, b1, W2, b2, W3, b3, out);
}

// Round 7
// 121.845 us; speedup vs baseline: 1.0218x; 1.0218x over previous
//
#include <hip/hip_runtime.h>
#include <math.h>

// ---------------- problem constants ----------------
#define NBLOCKS 4096              // R7: one block per (b, i, pos-half)
#define THREADS 256               // 4 waves/block, wave = ct (channel tile)
#define TILE 32                   // positions per iter
#define POS_PER_BLOCK 256
#define ITERS 8
#define CH 256                    // ushorts per k'-chunk: 32 pos * 8

typedef __attribute__((ext_vector_type(8)))  short  short8;   // MFMA A/B frag
typedef __attribute__((ext_vector_type(4)))  float  float4v;
typedef __attribute__((ext_vector_type(4)))  unsigned uint4v;
typedef __attribute__((ext_vector_type(16))) float  float16;  // 32x32 C/D frag

// gfx950 packed f32x2 -> bf16x2 (RNE), single VALU instruction
__device__ __forceinline__ unsigned cvt_pk(float lo, float hi) {
    unsigned r;
    asm("v_cvt_pk_bf16_f32 %0, %1, %2" : "=v"(r) : "v"(lo), "v"(hi));
    return r;
}

// NOTE (R1/R2): v_pk_max_i16-as-relu produced NaN output twice. Do NOT
// reintroduce. NOTE (R6): +32 regs (reg-bias + acc split) pushed unified
// VGPR+AGPR past the residency boundary at 512 thr (occ 51->37%, dur
// 60->66us). Keep per-wave state at the R5 level (~40 arch VGPR).
// R7 rationale: R5's ph=0/ph=1 wave-quartets are provably independent
// (producer ph == consumer ph in the ash exchange), so the 8-wave barrier
// over-synced two disjoint 4-wave gangs. Split them into separate 256-thr
// blocks: same code/regs/work, but 4 independent blocks/CU (was 2) and
// 4-wave barrier gangs (was 8) -> decorrelated stalls.
__device__ __forceinline__ int kmap(int c, int jj) {
    return 32 * (c >> 2) + 16 * ((c >> 1) & 1) + 4 * (c & 1) + ((jj >> 2) << 3) + (jj & 3);
}

__global__ __launch_bounds__(256, 4)
void crpb_mfma8(const float* __restrict__ gq,   // (512,3)
                const float* __restrict__ gkv,  // (4,512,3)
                const float* __restrict__ W1,   // (3,128)
                const float* __restrict__ b1,   // (128,)
                const float* __restrict__ W2,   // (128,128)
                const float* __restrict__ b2,   // (128,)
                const float* __restrict__ W3,   // (128,4)
                const float* __restrict__ b3,   // (4,)
                float* __restrict__ out)        // (16,512,512)
{
    __shared__ __align__(16) unsigned short ash[2][16 * CH];   // 2 x 8 KB h1 tile
    __shared__ __align__(16) float red[2][4 * 4 * 32];         // 2 x 2 KB partials [ct][o][pos]
    __shared__ __align__(16) float b2s[128];
    // per-block feature table (this block's 256 j-positions), B-frag layout.
    __shared__ __align__(16) unsigned fA[256][4];              // 4 KB
    __shared__ __align__(16) unsigned fB[256];                 // 1 KB

    const int tid  = threadIdx.x;
    const int lane = tid & 63;
    const int w    = __builtin_amdgcn_readfirstlane(tid >> 6);  // 0..3 = ct
    const int l31  = lane & 31;
    const int lh   = lane >> 5;

    if (tid < 128) b2s[tid] = b2[tid];

    const int ct = w;               // this wave's 32-channel tile

    // persistent zero C-operand (layer-1 and layer-3 MFMAs)
    float16 z16;
    #pragma unroll
    for (int r = 0; r < 16; ++r) z16[r] = 0.0f;

    // ---- layer-1 A-frag for this wave's ch tile (W1 hi/lo + b1 folded) ----
    // lh0 slots: (w0h,w0l),(w0h,w1h),(w1l,w1h),(w2h,w2l)  <-> B: (f0h,f0h),(f0l,f1h),(f1h,f1l),(f2h,f2h)
    // lh1 slots: (w2h,b1h),(b1l,0),0,0                    <-> B: (f2l,1.0),(1.0,0),0,0
    short8 w1f;
    {
        const int ch = ct * 32 + l31;
        const float w0 = W1[ch], w1v = W1[128 + ch], w2v = W1[256 + ch], b1v = b1[ch];
        const float w0h = __uint_as_float(cvt_pk(w0, w0) << 16);
        const float w1h = __uint_as_float(cvt_pk(w1v, w1v) << 16);
        const float w2h = __uint_as_float(cvt_pk(w2v, w2v) << 16);
        const float b1h = __uint_as_float(cvt_pk(b1v, b1v) << 16);
        const float w0l = w0 - w0h, w1l = w1v - w1h, w2l = w2v - w2h, b1l = b1v - b1h;
        unsigned d[4];
        if (lh == 0) {
            d[0] = cvt_pk(w0h, w0l);
            d[1] = cvt_pk(w0h, w1h);
            d[2] = cvt_pk(w1l, w1h);
            d[3] = cvt_pk(w2h, w2l);
        } else {
            d[0] = cvt_pk(w2h, b1h);
            d[1] = cvt_pk(b1l, 0.0f);
            d[2] = 0; d[3] = 0;
        }
        __builtin_memcpy(&w1f, d, 16);
    }

    // ---- W2^T A-frags for this wave's 32 out-chs (32 VGPRs) ----
    short8 a2f[8];
    {
        const int e = ct * 32 + l31;
        #pragma unroll
        for (int ks = 0; ks < 8; ++ks) {
            const int c = 2 * ks + lh;
            unsigned t0[4];
            #pragma unroll
            for (int t = 0; t < 4; ++t) {
                const int d0 = kmap(c, 2 * t), d1 = d0 + 1;
                t0[t] = cvt_pk(W2[d0 * 128 + e], W2[d1 * 128 + e]);
            }
            __builtin_memcpy(&a2f[ks], t0, 16);
        }
    }

    // ---- W3 A-frags: 2 frags cover this wave's 32 chs (8 VGPRs) ----
    short8 w3a[2];
    #pragma unroll
    for (int m2 = 0; m2 < 2; ++m2) {
        unsigned tt[4];
        #pragma unroll
        for (int t = 0; t < 4; ++t) {
            const int chl = ((2 * t) & 3) + 8 * ((2 * t) >> 2) + 4 * lh + 16 * m2;
            const int ch0 = ct * 32 + chl, ch1 = ch0 + 1;
            const float lo = (l31 < 4) ? W3[ch0 * 4 + l31] : 0.0f;
            const float hi = (l31 < 4) ? W3[ch1 * 4 + l31] : 0.0f;
            tt[t] = cvt_pk(lo, hi);
        }
        __builtin_memcpy(&w3a[m2], tt, 16);
    }
    const float b3r = b3[w];   // phase R: o = w

    // block-constant: (b, i, pos-half)
    const int posblock = blockIdx.x * POS_PER_BLOCK;
    const int bb    = posblock >> 18;
    const int i     = (posblock >> 9) & 511;
    const int jbase = posblock & 511;           // 0 or 256
    const float q0 = gq[i * 3 + 0], q1 = gq[i * 3 + 1], q2 = gq[i * 3 + 2];
    const float* kvrow = gkv + (size_t)((bb << 9) + jbase) * 3;

    // ---- feature precompute: this block's 256 positions, 1/thread ----
    {
        const int jj = tid;   // 0..255
        const float k0 = kvrow[jj * 3 + 0], k1 = kvrow[jj * 3 + 1], k2 = kvrow[jj * 3 + 2];
        const float c0 = q0 - k0, c1 = q1 - k1, c2 = q2 - k2;
        const float f0 = copysignf(__logf(1.0f + fabsf(c0)), c0);
        const float f1 = copysignf(__logf(1.0f + fabsf(c1)), c1);
        const float f2 = copysignf(__logf(1.0f + fabsf(c2)), c2);
        const unsigned u0 = cvt_pk(f0, f0), u2 = cvt_pk(f2, f2);
        const float f0h = __uint_as_float(u0 << 16);
        const float f1h = __uint_as_float(cvt_pk(f1, f1) << 16);
        const float f2h = __uint_as_float(u2 << 16);
        const float f0l = f0 - f0h, f1l = f1 - f1h, f2l = f2 - f2h;
        fA[jj][0] = u0;                    // (f0h, f0h)
        fA[jj][1] = cvt_pk(f0l, f1);       // (f0l, f1h)
        fA[jj][2] = cvt_pk(f1, f1l);       // (f1h, f1l)
        fA[jj][3] = u2;                    // (f2h, f2h)
        fB[jj]    = cvt_pk(f2l, 1.0f);     // (f2l, 1.0) ; word1 is const
    }
    __syncthreads();   // features + b2s visible to all waves

    // ======== phase A: B-frag from LDS -> layer-1 MFMA -> ash[buf] ========
    auto phaseA = [&](int x, int buf) {
        const int jj = x * TILE + l31;     // local feature index
        unsigned d[4];
        if (lh == 0) {
            const uint4v t = *(const uint4v*)&fA[jj][0];
            d[0] = t[0]; d[1] = t[1]; d[2] = t[2]; d[3] = t[3];
        } else {
            d[0] = fB[jj];
            d[1] = 0x00003F80u;            // (bf16 1.0, 0) <- picks up b1
            d[2] = 0; d[3] = 0;
        }
        short8 bf; __builtin_memcpy(&bf, d, 16);

        float16 c1r = __builtin_amdgcn_mfma_f32_32x32x16_bf16(w1f, bf, z16, 0, 0, 0);
        unsigned pk0[4], pk1[4];
        #pragma unroll
        for (int t = 0; t < 4; ++t) {
            pk0[t] = cvt_pk(fmaxf(c1r[2 * t], 0.f),     fmaxf(c1r[2 * t + 1], 0.f));
            pk1[t] = cvt_pk(fmaxf(c1r[8 + 2 * t], 0.f), fmaxf(c1r[8 + 2 * t + 1], 0.f));
        }
        short8 v0, v1;
        __builtin_memcpy(&v0, pk0, 16);
        __builtin_memcpy(&v1, pk1, 16);
        *(short8*)&ash[buf][(4 * ct + lh) * CH + l31 * 8]     = v0;   // m=0 octet
        *(short8*)&ash[buf][(4 * ct + 2 + lh) * CH + l31 * 8] = v1;   // m=1 octet
    };

    phaseA(0, 0);
    __syncthreads();   // fences ash[0]

    for (int it = 0; it < ITERS; ++it) {
        const int buf = it & 1;
        const int jb = jbase + it * TILE;

        // ======== phase B: layer-2; 8 B-reads feed 8 MFMAs (1 ch tile) ========
        float16 acc;
        #pragma unroll
        for (int qr = 0; qr < 4; ++qr) {
            float4v i0 = *(const float4v*)&b2s[ct * 32 + 8 * qr + 4 * lh];
            #pragma unroll
            for (int t = 0; t < 4; ++t) acc[4 * qr + t] = i0[t];
        }
        const unsigned short* br = &ash[buf][lh * CH + l31 * 8];

        // T5: boost issue priority through the dense MFMA region (R3: -2.7%).
        __builtin_amdgcn_s_setprio(1);
        #pragma unroll
        for (int ks = 0; ks < 8; ++ks) {
            short8 bfrag = *(const short8*)(br + ks * 2 * CH);
            acc = __builtin_amdgcn_mfma_f32_32x32x16_bf16(a2f[ks], bfrag, acc, 0, 0, 0);
        }

        // ======== phase C': in-register relu + layer-3 (2 MFMAs over 32 chs) ========
        {
            unsigned pa0[4], pa1[4];
            #pragma unroll
            for (int t = 0; t < 4; ++t) {
                pa0[t] = cvt_pk(fmaxf(acc[2 * t], 0.f),     fmaxf(acc[2 * t + 1], 0.f));
                pa1[t] = cvt_pk(fmaxf(acc[8 + 2 * t], 0.f), fmaxf(acc[8 + 2 * t + 1], 0.f));
            }
            short8 fa0, fa1;
            __builtin_memcpy(&fa0, pa0, 16); __builtin_memcpy(&fa1, pa1, 16);
            float16 p;
            p = __builtin_amdgcn_mfma_f32_32x32x16_bf16(w3a[0], fa0, z16, 0, 0, 0);
            p = __builtin_amdgcn_mfma_f32_32x32x16_bf16(w3a[1], fa1, p, 0, 0, 0);
            __builtin_amdgcn_s_setprio(0);
            if (lh == 0) {
                #pragma unroll
                for (int o = 0; o < 4; ++o)
                    red[buf][ct * 128 + o * 32 + l31] = p[o];
            }
        }

        // ======== phase A for next tile (other ash buffer) ========
        if (it != ITERS - 1) phaseA(it + 1, 1 - buf);

        __syncthreads();   // single barrier/tile: fences ash[1-buf] and red[buf]

        // ======== phase R: sum 4 ct-partials + b3, 32-wide store (lh0 lanes) ========
        if (lh == 0) {
            const int o = w, pos = l31;
            const float v = b3r
                          + red[buf][0 * 128 + o * 32 + pos]
                          + red[buf][1 * 128 + o * 32 + pos]
                          + red[buf][2 * 128 + o * 32 + pos]
                          + red[buf][3 * 128 + o * 32 + pos];
            out[((size_t)((bb << 2) + o) << 18) + ((size_t)i << 9) + jb + pos] = v;
        }
    }
}

extern "C" void kernel_launch(void* const* d_in, const int* in_sizes, int n_in,
                              void* d_out, int out_size, void* d_ws, size_t ws_size,
                              hipStream_t stream) {
    const float* gq  = (const float*)d_in[0];
    const float* gkv = (const float*)d_in[1];
    const float* W1  = (const float*)d_in[2];
    const float* b1  = (const float*)d_in[3];
    const float* W2  = (const float*)d_in[4];
    const float* b2  = (const float*)d_in[5];
    const float* W3  = (const float*)d_in[6];
    const float* b3  = (const float*)d_in[7];
    float* out = (float*)d_out;

    crpb_mfma8<<<NBLOCKS, THREADS, 0, stream>>>(gq, gkv, W1, b1, W2, b2, W3, b3, out);
}

// Round 8
// 118.791 us; speedup vs baseline: 1.0481x; 1.0257x over previous
//
#include <hip/hip_runtime.h>
#include <math.h>

// ---------------- problem constants ----------------
#define NBLOCKS 2048              // one block per (b, i): one 512-pos j-row
#define THREADS 256               // 4 waves/block, wave = ct (channel tile)
#define TILE 64                   // positions per iter (2 subtiles of 32/wave)
#define ITERS 8
#define CH 512                    // ushorts per k'-chunk: 64 pos * 8

typedef __attribute__((ext_vector_type(8)))  short  short8;   // MFMA A/B frag
typedef __attribute__((ext_vector_type(4)))  float  float4v;
typedef __attribute__((ext_vector_type(4)))  unsigned uint4v;
typedef __attribute__((ext_vector_type(16))) float  float16;  // 32x32 C/D frag

// gfx950 packed f32x2 -> bf16x2 (RNE), single VALU instruction
__device__ __forceinline__ unsigned cvt_pk(float lo, float hi) {
    unsigned r;
    asm("v_cvt_pk_bf16_f32 %0, %1, %2" : "=v"(r) : "v"(lo), "v"(hi));
    return r;
}

// NOTE (R1/R2): v_pk_max_i16-as-relu produced NaN output twice. Do NOT
// reintroduce. NOTE (R6): pushing unified VGPR+AGPR past the residency
// boundary costs a resident block (occ 51->37, dur +10%). Keep total regs
// under the launch-bounds cap.
// R8 rationale: R5 (2x occupancy -> +8%) and R7 (gang split -> -6%) prove
// TLP is a weak lever: all waves stall on the same per-iter dep chain
// (ds_read ~120cy + 8 serially-dep MFMAs + relu + barrier). This round
// converts TLP to in-wave ILP: each wave owns TWO independent pos-subtiles;
// their MFMA chains interleave -> dep stalls vanish, ds_read latency of one
// stream hides under the other's MFMAs. Barrier rate back at R5's level.
__device__ __forceinline__ int kmap(int c, int jj) {
    return 32 * (c >> 2) + 16 * ((c >> 1) & 1) + 4 * (c & 1) + ((jj >> 2) << 3) + (jj & 3);
}

__global__ __launch_bounds__(256, 3)
void crpb_mfma8(const float* __restrict__ gq,   // (512,3)
                const float* __restrict__ gkv,  // (4,512,3)
                const float* __restrict__ W1,   // (3,128)
                const float* __restrict__ b1,   // (128,)
                const float* __restrict__ W2,   // (128,128)
                const float* __restrict__ b2,   // (128,)
                const float* __restrict__ W3,   // (128,4)
                const float* __restrict__ b3,   // (4,)
                float* __restrict__ out)        // (16,512,512)
{
    __shared__ __align__(16) unsigned short ash[2][16 * CH];   // 2 x 16 KB h1 tile
    __shared__ __align__(16) float red[2][4 * 4 * 64];         // 2 x 4 KB [ct][o][pos]
    __shared__ __align__(16) float b2s[128];
    // per-block feature table (one j-row), B-frag word layout.
    __shared__ __align__(16) unsigned fA[512][4];              // 8 KB
    __shared__ __align__(16) unsigned fB[512];                 // 2 KB

    const int tid  = threadIdx.x;
    const int lane = tid & 63;
    const int w    = __builtin_amdgcn_readfirstlane(tid >> 6);  // 0..3 = ct
    const int l31  = lane & 31;
    const int lh   = lane >> 5;

    if (tid < 128) b2s[tid] = b2[tid];

    const int ct = w;               // this wave's 32-channel tile

    // persistent zero C-operand (layer-1 and layer-3 MFMAs)
    float16 z16;
    #pragma unroll
    for (int r = 0; r < 16; ++r) z16[r] = 0.0f;

    // ---- layer-1 A-frag for this wave's ch tile (W1 hi/lo + b1 folded) ----
    // lh0 slots: (w0h,w0l),(w0h,w1h),(w1l,w1h),(w2h,w2l)  <-> B: (f0h,f0h),(f0l,f1h),(f1h,f1l),(f2h,f2h)
    // lh1 slots: (w2h,b1h),(b1l,0),0,0                    <-> B: (f2l,1.0),(1.0,0),0,0
    short8 w1f;
    {
        const int ch = ct * 32 + l31;
        const float w0 = W1[ch], w1v = W1[128 + ch], w2v = W1[256 + ch], b1v = b1[ch];
        const float w0h = __uint_as_float(cvt_pk(w0, w0) << 16);
        const float w1h = __uint_as_float(cvt_pk(w1v, w1v) << 16);
        const float w2h = __uint_as_float(cvt_pk(w2v, w2v) << 16);
        const float b1h = __uint_as_float(cvt_pk(b1v, b1v) << 16);
        const float w0l = w0 - w0h, w1l = w1v - w1h, w2l = w2v - w2h, b1l = b1v - b1h;
        unsigned d[4];
        if (lh == 0) {
            d[0] = cvt_pk(w0h, w0l);
            d[1] = cvt_pk(w0h, w1h);
            d[2] = cvt_pk(w1l, w1h);
            d[3] = cvt_pk(w2h, w2l);
        } else {
            d[0] = cvt_pk(w2h, b1h);
            d[1] = cvt_pk(b1l, 0.0f);
            d[2] = 0; d[3] = 0;
        }
        __builtin_memcpy(&w1f, d, 16);
    }

    // ---- W2^T A-frags for this wave's 32 out-chs (32 VGPRs) ----
    short8 a2f[8];
    {
        const int e = ct * 32 + l31;
        #pragma unroll
        for (int ks = 0; ks < 8; ++ks) {
            const int c = 2 * ks + lh;
            unsigned t0[4];
            #pragma unroll
            for (int t = 0; t < 4; ++t) {
                const int d0 = kmap(c, 2 * t), d1 = d0 + 1;
                t0[t] = cvt_pk(W2[d0 * 128 + e], W2[d1 * 128 + e]);
            }
            __builtin_memcpy(&a2f[ks], t0, 16);
        }
    }

    // ---- W3 A-frags: 2 frags cover this wave's 32 chs (8 VGPRs) ----
    short8 w3a[2];
    #pragma unroll
    for (int m2 = 0; m2 < 2; ++m2) {
        unsigned tt[4];
        #pragma unroll
        for (int t = 0; t < 4; ++t) {
            const int chl = ((2 * t) & 3) + 8 * ((2 * t) >> 2) + 4 * lh + 16 * m2;
            const int ch0 = ct * 32 + chl, ch1 = ch0 + 1;
            const float lo = (l31 < 4) ? W3[ch0 * 4 + l31] : 0.0f;
            const float hi = (l31 < 4) ? W3[ch1 * 4 + l31] : 0.0f;
            tt[t] = cvt_pk(lo, hi);
        }
        __builtin_memcpy(&w3a[m2], tt, 16);
    }
    const float b3r = b3[w];   // phase R: o = w

    // block-constant: one j-row (b, i fixed)
    const int posblock = blockIdx.x * 512;
    const int bb = posblock >> 18;
    const int i  = (posblock >> 9) & 511;
    const float q0 = gq[i * 3 + 0], q1 = gq[i * 3 + 1], q2 = gq[i * 3 + 2];
    const float* kvrow = gkv + (size_t)(bb << 9) * 3;

    // ---- feature precompute: whole j-row, once per block (2 pos/thread) ----
    for (int jj = tid; jj < 512; jj += THREADS) {
        const float k0 = kvrow[jj * 3 + 0], k1 = kvrow[jj * 3 + 1], k2 = kvrow[jj * 3 + 2];
        const float c0 = q0 - k0, c1 = q1 - k1, c2 = q2 - k2;
        const float f0 = copysignf(__logf(1.0f + fabsf(c0)), c0);
        const float f1 = copysignf(__logf(1.0f + fabsf(c1)), c1);
        const float f2 = copysignf(__logf(1.0f + fabsf(c2)), c2);
        const unsigned u0 = cvt_pk(f0, f0), u2 = cvt_pk(f2, f2);
        const float f0h = __uint_as_float(u0 << 16);
        const float f1h = __uint_as_float(cvt_pk(f1, f1) << 16);
        const float f2h = __uint_as_float(u2 << 16);
        const float f0l = f0 - f0h, f1l = f1 - f1h, f2l = f2 - f2h;
        fA[jj][0] = u0;                    // (f0h, f0h)
        fA[jj][1] = cvt_pk(f0l, f1);       // (f0l, f1h)
        fA[jj][2] = cvt_pk(f1, f1l);       // (f1h, f1l)
        fA[jj][3] = u2;                    // (f2h, f2h)
        fB[jj]    = cvt_pk(f2l, 1.0f);     // (f2l, 1.0) ; word1 is const
    }
    __syncthreads();   // features + b2s visible to all waves

    // ======== phase A: both subtiles, 2 independent layer-1 MFMAs ========
    auto phaseA = [&](int x, int buf) {
        #pragma unroll
        for (int sub = 0; sub < 2; ++sub) {
            const int pofs = sub * 32 + l31;
            const int jpos = x * TILE + pofs;
            unsigned d[4];
            if (lh == 0) {
                const uint4v t = *(const uint4v*)&fA[jpos][0];
                d[0] = t[0]; d[1] = t[1]; d[2] = t[2]; d[3] = t[3];
            } else {
                d[0] = fB[jpos];
                d[1] = 0x00003F80u;            // (bf16 1.0, 0) <- picks up b1
                d[2] = 0; d[3] = 0;
            }
            short8 bf; __builtin_memcpy(&bf, d, 16);

            float16 c1r = __builtin_amdgcn_mfma_f32_32x32x16_bf16(w1f, bf, z16, 0, 0, 0);
            unsigned pk0[4], pk1[4];
            #pragma unroll
            for (int t = 0; t < 4; ++t) {
                pk0[t] = cvt_pk(fmaxf(c1r[2 * t], 0.f),     fmaxf(c1r[2 * t + 1], 0.f));
                pk1[t] = cvt_pk(fmaxf(c1r[8 + 2 * t], 0.f), fmaxf(c1r[8 + 2 * t + 1], 0.f));
            }
            short8 v0, v1;
            __builtin_memcpy(&v0, pk0, 16);
            __builtin_memcpy(&v1, pk1, 16);
            *(short8*)&ash[buf][(4 * ct + lh) * CH + pofs * 8]     = v0;   // m=0 octet
            *(short8*)&ash[buf][(4 * ct + 2 + lh) * CH + pofs * 8] = v1;   // m=1 octet
        }
    };

    phaseA(0, 0);
    __syncthreads();   // fences ash[0]

    for (int it = 0; it < ITERS; ++it) {
        const int buf = it & 1;
        const int jb = it * TILE;

        // ======== phase B: two INDEPENDENT 8-MFMA chains, interleaved ========
        float16 acc0, acc1;
        #pragma unroll
        for (int qr = 0; qr < 4; ++qr) {
            float4v i0 = *(const float4v*)&b2s[ct * 32 + 8 * qr + 4 * lh];
            #pragma unroll
            for (int t = 0; t < 4; ++t) { acc0[4 * qr + t] = i0[t]; acc1[4 * qr + t] = i0[t]; }
        }
        const unsigned short* br0 = &ash[buf][lh * CH + (0 * 32 + l31) * 8];
        const unsigned short* br1 = &ash[buf][lh * CH + (1 * 32 + l31) * 8];

        // T5: boost issue priority through the dense MFMA region (R3: -2.7%).
        __builtin_amdgcn_s_setprio(1);
        #pragma unroll
        for (int ks = 0; ks < 8; ++ks) {
            short8 bf0 = *(const short8*)(br0 + ks * 2 * CH);
            short8 bf1 = *(const short8*)(br1 + ks * 2 * CH);
            acc0 = __builtin_amdgcn_mfma_f32_32x32x16_bf16(a2f[ks], bf0, acc0, 0, 0, 0);
            acc1 = __builtin_amdgcn_mfma_f32_32x32x16_bf16(a2f[ks], bf1, acc1, 0, 0, 0);
        }

        // ======== phase C': per-subtile relu + layer-3 (2 indep 2-chains) ========
        #pragma unroll
        for (int sub = 0; sub < 2; ++sub) {
            const float16& acc = sub ? acc1 : acc0;
            unsigned pa0[4], pa1[4];
            #pragma unroll
            for (int t = 0; t < 4; ++t) {
                pa0[t] = cvt_pk(fmaxf(acc[2 * t], 0.f),     fmaxf(acc[2 * t + 1], 0.f));
                pa1[t] = cvt_pk(fmaxf(acc[8 + 2 * t], 0.f), fmaxf(acc[8 + 2 * t + 1], 0.f));
            }
            short8 fa0, fa1;
            __builtin_memcpy(&fa0, pa0, 16); __builtin_memcpy(&fa1, pa1, 16);
            float16 p;
            p = __builtin_amdgcn_mfma_f32_32x32x16_bf16(w3a[0], fa0, z16, 0, 0, 0);
            p = __builtin_amdgcn_mfma_f32_32x32x16_bf16(w3a[1], fa1, p, 0, 0, 0);
            if (lh == 0) {
                #pragma unroll
                for (int o = 0; o < 4; ++o)
                    red[buf][ct * 256 + o * 64 + sub * 32 + l31] = p[o];
            }
        }
        __builtin_amdgcn_s_setprio(0);

        // ======== phase A for next tile (other ash buffer) ========
        if (it != ITERS - 1) phaseA(it + 1, 1 - buf);

        __syncthreads();   // single barrier/tile: fences ash[1-buf] and red[buf]

        // ======== phase R: sum 4 ct-partials + b3, full-wave coalesced store ========
        {
            const int o = w, pos = lane;
            const float v = b3r
                          + red[buf][0 * 256 + o * 64 + pos]
                          + red[buf][1 * 256 + o * 64 + pos]
                          + red[buf][2 * 256 + o * 64 + pos]
                          + red[buf][3 * 256 + o * 64 + pos];
            out[((size_t)((bb << 2) + o) << 18) + ((size_t)i << 9) + jb + pos] = v;
        }
    }
}

extern "C" void kernel_launch(void* const* d_in, const int* in_sizes, int n_in,
                              void* d_out, int out_size, void* d_ws, size_t ws_size,
                              hipStream_t stream) {
    const float* gq  = (const float*)d_in[0];
    const float* gkv = (const float*)d_in[1];
    const float* W1  = (const float*)d_in[2];
    const float* b1  = (const float*)d_in[3];
    const float* W2  = (const float*)d_in[4];
    const float* b2  = (const float*)d_in[5];
    const float* W3  = (const float*)d_in[6];
    const float* b3  = (const float*)d_in[7];
    float* out = (float*)d_out;

    crpb_mfma8<<<NBLOCKS, THREADS, 0, stream>>>(gq, gkv, W1, b1, W2, b2, W3, b3, out);
}